// Round 7
// baseline (202.141 us; speedup 1.0000x reference)
//
#include <hip/hip_runtime.h>

// VQ-VAE codebook quantization — MFMA-screened, np-bit-exact.
// Screen: split-bf16 (xh+xl)(ch+cl) via mfma_f32_16x16x32_bf16, 3 terms.
// Sound window W flags possible np-argmin ambiguity (~1% of positions);
// flagged positions re-scanned with the exact np fp32 pipeline.
//
// R7: occupancy 16 -> 32 waves/CU. R6 post-mortem: L1-alignment null (82.5
// vs 81), barrier-convoy theory dead (R5), spill theory fixed (R4). All
// pipes remain <25% busy with Occupancy 27% -> latency-bound with too few
// waves. Change: same 1024 blocks / same LDS (4 blocks/CU), but 512
// threads/block (8 waves). Each wave owns ONE 16-pos row-tile (was two):
// A-frags 32->16 VGPRs, min-track 24->12, so the kernel fits <=64 VGPR =
// 8 waves/SIMD (m69 cliff). launch_bounds(512,8) enforces it.
// Per-position arithmetic is the identical rt-slice of R4's (same MFMA
// accumulation order, same np trees/window/refine) -> bit-exact.
// Canaries: VGPR_Count<=64, WRITE_SIZE==65536 KB exactly.

typedef short bf16x8 __attribute__((ext_vector_type(8)));
typedef float f32x4  __attribute__((ext_vector_type(4)));

#define KCODES 512
#define DDIM 64
#define HWSZ 4096
#define NPOS 131072
#define POSB 128             // positions per block
#define NBLK (NPOS / POSB)   // 1024 = 256 CU x 4 blocks/CU (one resident round)
#define OUT2_OFF 8388608
#define S_X 132              // x_lds pos-stride in floats (mult of 4: aligned b128)
#define S_X4 (S_X / 4)       // float4 stride = 33

__device__ __forceinline__ unsigned short f2bf_rne(float f) {
    unsigned u = __builtin_bit_cast(unsigned, f);
    unsigned r = u + 0x7FFFu + ((u >> 16) & 1u);
    return (unsigned short)(r >> 16);
}
__device__ __forceinline__ float bf2f(unsigned short h) {
    unsigned u = ((unsigned)h) << 16;
    return __builtin_bit_cast(float, u);
}

// numpy pairwise_sum (n=64 branch) of rounded squares, fp32, no fma.
__device__ __forceinline__ float np_sumsq64(const float* __restrict__ a) {
#pragma clang fp contract(off)
    float r0 = a[0]*a[0], r1 = a[1]*a[1], r2 = a[2]*a[2], r3 = a[3]*a[3];
    float r4 = a[4]*a[4], r5 = a[5]*a[5], r6 = a[6]*a[6], r7 = a[7]*a[7];
#pragma unroll
    for (int i = 8; i < 64; i += 8) {
        r0 += a[i+0]*a[i+0]; r1 += a[i+1]*a[i+1];
        r2 += a[i+2]*a[i+2]; r3 += a[i+3]*a[i+3];
        r4 += a[i+4]*a[i+4]; r5 += a[i+5]*a[i+5];
        r6 += a[i+6]*a[i+6]; r7 += a[i+7]*a[i+7];
    }
    return ((r0+r1)+(r2+r3)) + ((r4+r5)+(r6+r7));
}

// Prep: B-fragments (split bf16) in exact 16x16x32 B-operand layout + np cbsqr.
// ws layout: [0,128KB) bf16 frags [tile32][chunk2][split2][lane64][j8];
//            [128KB,130KB) fp32 cbsqr[512].
__global__ __launch_bounds__(256) void vq_prep(
    const float* __restrict__ cb, unsigned short* __restrict__ wsb,
    float* __restrict__ wscb)
{
    if (blockIdx.x < 128) {
        int u = blockIdx.x * 256 + threadIdx.x;   // u = k*64 + d
        int k = u >> 6, d = u & 63;
        float c = cb[u];
        unsigned short ch = f2bf_rne(c);
        float clf = c - bf2f(ch);                  // exact
        unsigned short cl = f2bf_rne(clf);
        int tile = k >> 4, n = k & 15;
        int chunk = d >> 5, quad = (d >> 3) & 3, j = d & 7;
        int lane = quad * 16 + n;                  // B: lane holds B[k=q*8+j][n]
        size_t base = ((((size_t)tile*2 + chunk)*2 + 0)*64 + lane)*8 + j;
        wsb[base]       = (unsigned short)ch;
        wsb[base + 512] = (unsigned short)cl;      // split stride = 64*8
    } else {
        int k = (blockIdx.x - 128) * 256 + threadIdx.x;
        if (k < KCODES) wscb[k] = np_sumsq64(cb + k * DDIM);
    }
}

__global__ __launch_bounds__(512, 8) void vq_main(
    const float* __restrict__ z, const float* __restrict__ cb,
    const unsigned short* __restrict__ wsb, const float* __restrict__ wscb,
    float* __restrict__ out)
{
#pragma clang fp contract(off)
    __shared__ float4 s_xbuf4[DDIM * S_X4];   // 33792 B: x tile, reused for codes in P6
    __shared__ float s_cbsqr[KCODES];
    __shared__ float s_xsqr[POSB];
    __shared__ float s_part[2 * POSB];
    __shared__ int   s_idx[POSB];
    __shared__ int   s_flist[POSB];
    __shared__ int   s_cnt;
    float* s_regA = (float*)s_xbuf4;
    // total LDS ~38.9 KB -> 4 blocks/CU; 512 thr = 8 waves -> 32 waves/CU

    const int tid = threadIdx.x;
    const int wv = tid >> 6, ln = tid & 63;     // wv 0..7: wave owns 16 positions
    const int m = ln & 15, q = ln >> 4;
    const int n0 = blockIdx.x * POSB;
    const long gbase = (long)(n0 >> 12) * (DDIM * HWSZ) + (n0 & 4095);

    if (tid == 0) s_cnt = 0;
    if (tid < 512) s_cbsqr[tid] = wscb[tid];

    // ---- phase 1: z -> x_lds, d-major [d][pos], float4 coalesced ----
    {
        const float4* z4 = (const float4*)(z + gbase);  // gbase mult of 128 -> aligned
#pragma unroll
        for (int i = 0; i < 4; ++i) {
            int v = i * 512 + tid;
            int d = v >> 5, p4 = v & 31;
            s_xbuf4[d * S_X4 + p4] = z4[d * (HWSZ / 4) + p4];
        }
    }
    __syncthreads();

    // ---- phase 2a: np xsqr partials (first 256 threads -> (p, h)) ----
    if (tid < 256) {
        int p = tid & 127, h = tid >> 7;
        float r0 = 0.f, r1 = 0.f, r2 = 0.f, r3 = 0.f;
#pragma unroll
        for (int i = 0; i < 8; ++i) {
            float a0 = s_regA[(8*i + 4*h + 0) * S_X + p];
            float a1 = s_regA[(8*i + 4*h + 1) * S_X + p];
            float a2 = s_regA[(8*i + 4*h + 2) * S_X + p];
            float a3 = s_regA[(8*i + 4*h + 3) * S_X + p];
            r0 += a0*a0; r1 += a1*a1; r2 += a2*a2; r3 += a3*a3;
        }
        s_part[h * POSB + p] = (r0 + r1) + (r2 + r3);
    }

    // ---- phase 2b: A-fragments (per wave: 1 row-tile x 2 K-chunks, split) ----
    bf16x8 Ah[2], Al[2];
#pragma unroll
    for (int c = 0; c < 2; ++c) {
        int pos = wv * 16 + m;
        bf16x8 ah, al;
#pragma unroll
        for (int j = 0; j < 8; ++j) {
            float xv = s_regA[(c*32 + q*8 + j) * S_X + pos];
            unsigned short hh = f2bf_rne(xv);
            float lo = xv - bf2f(hh);          // exact
            ah[j] = (short)hh;
            al[j] = (short)f2bf_rne(lo);
        }
        Ah[c] = ah; Al[c] = al;
    }
    __syncthreads();
    if (tid < POSB) s_xsqr[tid] = s_part[tid] + s_part[POSB + tid]; // np (A+B)
    __syncthreads();   // s_xsqr visible to all (P4 readers); P3 is barrier-free

    // ---- phase 3: screen all 512 codes, B-frags direct from global (L2-hot) ----
    float m1[4], m2[4]; int t1[4];
#pragma unroll
    for (int i = 0; i < 4; ++i) { m1[i] = 3.4e38f; m2[i] = 3.4e38f; t1[i] = 0; }

    {
        const unsigned short* wbl = wsb + ln * 8;   // per-lane frag base
#pragma unroll 2
        for (int t = 0; t < 32; ++t) {
            const unsigned short* nb = wbl + t * 2048;
            bf16x8 Bh0 = *(const bf16x8*)(nb + 0);
            bf16x8 Bl0 = *(const bf16x8*)(nb + 512);
            bf16x8 Bh1 = *(const bf16x8*)(nb + 1024);
            bf16x8 Bl1 = *(const bf16x8*)(nb + 1536);
            float cbv = s_cbsqr[t * 16 + m];
            f32x4 acc = {0.f, 0.f, 0.f, 0.f};
            acc = __builtin_amdgcn_mfma_f32_16x16x32_bf16(Al[0], Bh0, acc, 0,0,0);
            acc = __builtin_amdgcn_mfma_f32_16x16x32_bf16(Ah[0], Bl0, acc, 0,0,0);
            acc = __builtin_amdgcn_mfma_f32_16x16x32_bf16(Ah[0], Bh0, acc, 0,0,0);
            acc = __builtin_amdgcn_mfma_f32_16x16x32_bf16(Al[1], Bh1, acc, 0,0,0);
            acc = __builtin_amdgcn_mfma_f32_16x16x32_bf16(Ah[1], Bl1, acc, 0,0,0);
            acc = __builtin_amdgcn_mfma_f32_16x16x32_bf16(Ah[1], Bh1, acc, 0,0,0);
#pragma unroll
            for (int r = 0; r < 4; ++r) {
                float sc = fmaf(-2.f, acc[r], cbv);
                bool lt = sc < m1[r];
                m2[r] = fminf(m2[r], lt ? m1[r] : sc);
                if (lt) { m1[r] = sc; t1[r] = t; }
            }
        }
    }

    // ---- phase 4: per-position reduce over 16 lanes; flag ambiguity ----
#pragma unroll
    for (int r = 0; r < 4; ++r) {
        float v1 = m1[r], v2 = m2[r];
        int i1 = t1[r] * 16 + m;
#pragma unroll
        for (int s = 1; s < 16; s <<= 1) {
            float o1 = __shfl_xor(v1, s);
            float o2 = __shfl_xor(v2, s);
            int   oi = __shfl_xor(i1, s);
            bool take = (o1 < v1) || (o1 == v1 && oi < i1);
            float lose = take ? v1 : o1;
            if (take) { v1 = o1; i1 = oi; }
            v2 = fminf(fminf(v2, o2), lose);
        }
        if (m == 0) {
            int pos = wv * 16 + q * 4 + r;
            float xs = s_xsqr[pos];
            float sx = 8.0f * sqrtf(xs) * 1.01f;       // >= sum |x_d|
            float amax = 0.00196f * sx + 0.01f;        // >= sum|x c| + margin
            float eps = 1.5f * (3.0f * 1.52587890625e-5f * 0.00196f * sx
                                + 500.f * 5.96e-8f * amax);
            float delta = 2.4e-7f * (xs + 1.0f) + 64.f * 1.2e-7f * amax;
            float W = 2.f * eps + 2.f * delta + 1e-9f;
            int flag = (v2 - v1 <= W) ? (1 << 30) : 0;
            s_idx[pos] = i1 | flag;
        }
    }
    __syncthreads();
    if (tid < POSB) {
        if (s_idx[tid] & (1 << 30)) {
            int slot = atomicAdd(&s_cnt, 1);
            s_flist[slot] = tid;
        }
    }
    __syncthreads();

    // ---- phase 5: np-exact refine of flagged positions (x read from LDS) ----
    const int cnt = s_cnt;
    for (int i = wv; i < cnt; i += 8) {
        int p = __builtin_amdgcn_readfirstlane(s_flist[i]);
        float xv = s_regA[ln * S_X + p];             // lane ln holds x[d=ln]
        float xs = s_xsqr[p];
        float dot[8];
#pragma unroll
        for (int j = 0; j < 8; ++j) dot[j] = 0.f;
        const float* crow = cb + (ln * 8) * DDIM;    // lane's 8 codes
        for (int dc = 0; dc < 16; ++dc) {
            float x0 = __shfl(xv, dc*4 + 0);
            float x1 = __shfl(xv, dc*4 + 1);
            float x2 = __shfl(xv, dc*4 + 2);
            float x3 = __shfl(xv, dc*4 + 3);
#pragma unroll
            for (int j = 0; j < 8; ++j) {
                float4 cv = *(const float4*)(crow + j * DDIM + dc * 4);
                dot[j] = fmaf(x0, cv.x, dot[j]);
                dot[j] = fmaf(x1, cv.y, dot[j]);
                dot[j] = fmaf(x2, cv.z, dot[j]);
                dot[j] = fmaf(x3, cv.w, dot[j]);
            }
        }
        float bv = 3.4e38f; int bi = 0;
#pragma unroll
        for (int j = 0; j < 8; ++j) {
            int k = ln * 8 + j;
            float tt = s_cbsqr[k] + xs;
            float e = fmaf(-2.f, dot[j], tt);
            if (e < bv) { bv = e; bi = k; }
        }
#pragma unroll
        for (int s = 1; s < 64; s <<= 1) {
            float ov = __shfl_xor(bv, s); int oi = __shfl_xor(bi, s);
            if (ov < bv || (ov == bv && oi < bi)) { bv = ov; bi = oi; }
        }
        if (ln == 0) s_idx[p] = bi;
    }
    __syncthreads();   // P5 LDS reads done; s_idx final -> safe to overwrite s_regA

    // ---- phase 6a: stage selected code rows into LDS, d-major [d][pos] ----
    {
        int p = tid & 127, hf = tid >> 7;          // hf 0..3: 16 dims each
        int idx = s_idx[p] & 0x3FFFFFFF;
        const float4* crow4 = (const float4*)(cb + idx * DDIM + hf * 16);
#pragma unroll
        for (int j4 = 0; j4 < 4; ++j4) {
            float4 cv = crow4[j4];
            int d = hf * 16 + j4 * 4;
            s_regA[(d + 0) * S_X + p] = cv.x;   // fixed d per instr, p per lane:
            s_regA[(d + 1) * S_X + p] = cv.y;   // consecutive banks, conflict-free
            s_regA[(d + 2) * S_X + p] = cv.z;
            s_regA[(d + 3) * S_X + p] = cv.w;
        }
    }
    __syncthreads();

    // ---- phase 6b: float4 writeback to both outputs (NCHW) ----
    {
        float4* o4 = (float4*)(out + gbase);
#pragma unroll
        for (int i = 0; i < 4; ++i) {
            int v = i * 512 + tid;
            int d = v >> 5, p4 = v & 31;
            float4 val = s_xbuf4[d * S_X4 + p4];
            size_t off = (size_t)d * (HWSZ / 4) + p4;
            o4[off] = val;
            o4[off + (OUT2_OFF / 4)] = val;
        }
    }
}

extern "C" void kernel_launch(void* const* d_in, const int* in_sizes, int n_in,
                              void* d_out, int out_size, void* d_ws, size_t ws_size,
                              hipStream_t stream) {
    const float* z  = (const float*)d_in[0];   // [32,64,64,64] fp32
    const float* cb = (const float*)d_in[1];   // [512,64] fp32
    float* out = (float*)d_out;                // 2 * 8388608 fp32
    unsigned short* wsb = (unsigned short*)d_ws;            // 128 KB frags
    float* wscb = (float*)((char*)d_ws + 131072);           // 2 KB cbsqr
    vq_prep<<<130, 256, 0, stream>>>(cb, wsb, wscb);
    vq_main<<<NBLK, 512, 0, stream>>>(z, cb, wsb, wscb, out);
}

// Round 8
// 182.562 us; speedup vs baseline: 1.1072x; 1.1072x over previous
//
#include <hip/hip_runtime.h>

// VQ-VAE codebook quantization — MFMA-screened, np-bit-exact.
// Screen: split-bf16 (xh+xl)(ch+cl) via mfma_f32_16x16x32_bf16, 3 terms.
// Sound window W flags possible np-argmin ambiguity (~1% of positions);
// flagged positions re-scanned with the exact np fp32 pipeline.
//
// R8: ATTRIBUTION ROUND — split vq_main (R4 base, 81us proven) into
// vq_screen (P1-P5) + vq_scatter (P6) so rocprof reports per-phase time.
// R7 post-mortem: 8-wave/64-VGPR config spilled again (WRITE 104501 KB,
// VGPR 32) -> occupancy theory untested/void. Three structural theories
// (barrier convoys R5, L1 alignment R6, occupancy R7) dead or void while
// cycle models predict ~30us for an 81us kernel -> measure, don't guess.
// Handoff: block's 128 selected indices stored as ints in the block's OWN
// output row out[gbase..gbase+128) (copy-1 d=0 row) — each block reads back
// only what it alone later overwrites -> no cross-block race.
// All numerics byte-identical to R4 -> bit-exact.

typedef short bf16x8 __attribute__((ext_vector_type(8)));
typedef float f32x4  __attribute__((ext_vector_type(4)));

#define KCODES 512
#define DDIM 64
#define HWSZ 4096
#define NPOS 131072
#define POSB 128             // positions per block
#define NBLK (NPOS / POSB)   // 1024 = 256 CU x 4 blocks/CU (one resident round)
#define OUT2_OFF 8388608
#define S_X 132              // x_lds pos-stride in floats (mult of 4: aligned b128)
#define S_X4 (S_X / 4)       // float4 stride = 33

__device__ __forceinline__ unsigned short f2bf_rne(float f) {
    unsigned u = __builtin_bit_cast(unsigned, f);
    unsigned r = u + 0x7FFFu + ((u >> 16) & 1u);
    return (unsigned short)(r >> 16);
}
__device__ __forceinline__ float bf2f(unsigned short h) {
    unsigned u = ((unsigned)h) << 16;
    return __builtin_bit_cast(float, u);
}

// numpy pairwise_sum (n=64 branch) of rounded squares, fp32, no fma.
__device__ __forceinline__ float np_sumsq64(const float* __restrict__ a) {
#pragma clang fp contract(off)
    float r0 = a[0]*a[0], r1 = a[1]*a[1], r2 = a[2]*a[2], r3 = a[3]*a[3];
    float r4 = a[4]*a[4], r5 = a[5]*a[5], r6 = a[6]*a[6], r7 = a[7]*a[7];
#pragma unroll
    for (int i = 8; i < 64; i += 8) {
        r0 += a[i+0]*a[i+0]; r1 += a[i+1]*a[i+1];
        r2 += a[i+2]*a[i+2]; r3 += a[i+3]*a[i+3];
        r4 += a[i+4]*a[i+4]; r5 += a[i+5]*a[i+5];
        r6 += a[i+6]*a[i+6]; r7 += a[i+7]*a[i+7];
    }
    return ((r0+r1)+(r2+r3)) + ((r4+r5)+(r6+r7));
}

// Prep: B-fragments (split bf16) in exact 16x16x32 B-operand layout + np cbsqr.
// ws layout: [0,128KB) bf16 frags [tile32][chunk2][split2][lane64][j8];
//            [128KB,130KB) fp32 cbsqr[512].
__global__ __launch_bounds__(256) void vq_prep(
    const float* __restrict__ cb, unsigned short* __restrict__ wsb,
    float* __restrict__ wscb)
{
    if (blockIdx.x < 128) {
        int u = blockIdx.x * 256 + threadIdx.x;   // u = k*64 + d
        int k = u >> 6, d = u & 63;
        float c = cb[u];
        unsigned short ch = f2bf_rne(c);
        float clf = c - bf2f(ch);                  // exact
        unsigned short cl = f2bf_rne(clf);
        int tile = k >> 4, n = k & 15;
        int chunk = d >> 5, quad = (d >> 3) & 3, j = d & 7;
        int lane = quad * 16 + n;                  // B: lane holds B[k=q*8+j][n]
        size_t base = ((((size_t)tile*2 + chunk)*2 + 0)*64 + lane)*8 + j;
        wsb[base]       = (unsigned short)ch;
        wsb[base + 512] = (unsigned short)cl;      // split stride = 64*8
    } else {
        int k = (blockIdx.x - 128) * 256 + threadIdx.x;
        if (k < KCODES) wscb[k] = np_sumsq64(cb + k * DDIM);
    }
}

// ---------------- kernel A: P1-P5 (screen + refine), idx -> out row ----------
__global__ __launch_bounds__(256, 4) void vq_screen(
    const float* __restrict__ z, const float* __restrict__ cb,
    const unsigned short* __restrict__ wsb, const float* __restrict__ wscb,
    float* __restrict__ out)
{
#pragma clang fp contract(off)
    __shared__ float4 s_xbuf4[DDIM * S_X4];   // 33792 B: x tile
    __shared__ float s_cbsqr[KCODES];
    __shared__ float s_xsqr[POSB];
    __shared__ float s_part[2 * POSB];
    __shared__ int   s_idx[POSB];
    __shared__ int   s_flist[POSB];
    __shared__ int   s_cnt;
    float* s_regA = (float*)s_xbuf4;

    const int tid = threadIdx.x;
    const int wv = tid >> 6, ln = tid & 63;
    const int m = ln & 15, q = ln >> 4;
    const int n0 = blockIdx.x * POSB;
    const long gbase = (long)(n0 >> 12) * (DDIM * HWSZ) + (n0 & 4095);

    if (tid == 0) s_cnt = 0;
    s_cbsqr[tid] = wscb[tid];
    s_cbsqr[tid + 256] = wscb[tid + 256];

    // ---- phase 1: z -> x_lds, d-major [d][pos], float4 coalesced ----
    {
        const float4* z4 = (const float4*)(z + gbase);  // gbase mult of 128 -> aligned
#pragma unroll
        for (int i = 0; i < 8; ++i) {
            int v = i * 256 + tid;
            int d = v >> 5, p4 = v & 31;
            s_xbuf4[d * S_X4 + p4] = z4[d * (HWSZ / 4) + p4];
        }
    }
    __syncthreads();

    // ---- phase 2a: np xsqr partials (thread -> (p, h)) ----
    {
        int p = tid & 127, h = tid >> 7;
        float r0 = 0.f, r1 = 0.f, r2 = 0.f, r3 = 0.f;
#pragma unroll
        for (int i = 0; i < 8; ++i) {
            float a0 = s_regA[(8*i + 4*h + 0) * S_X + p];
            float a1 = s_regA[(8*i + 4*h + 1) * S_X + p];
            float a2 = s_regA[(8*i + 4*h + 2) * S_X + p];
            float a3 = s_regA[(8*i + 4*h + 3) * S_X + p];
            r0 += a0*a0; r1 += a1*a1; r2 += a2*a2; r3 += a3*a3;
        }
        s_part[h * POSB + p] = (r0 + r1) + (r2 + r3);
    }

    // ---- phase 2b: A-fragments (per wave: 2 row-tiles x 2 K-chunks, split) ----
    bf16x8 Ah[4], Al[4];
#pragma unroll
    for (int rt = 0; rt < 2; ++rt)
#pragma unroll
        for (int c = 0; c < 2; ++c) {
            int pos = wv * 32 + rt * 16 + m;
            bf16x8 ah, al;
#pragma unroll
            for (int j = 0; j < 8; ++j) {
                float xv = s_regA[(c*32 + q*8 + j) * S_X + pos];
                unsigned short hh = f2bf_rne(xv);
                float lo = xv - bf2f(hh);          // exact
                ah[j] = (short)hh;
                al[j] = (short)f2bf_rne(lo);
            }
            Ah[rt*2 + c] = ah; Al[rt*2 + c] = al;
        }
    __syncthreads();
    if (tid < POSB) s_xsqr[tid] = s_part[tid] + s_part[POSB + tid]; // np (A+B)
    __syncthreads();   // s_xsqr visible to all (P4 readers); P3 is barrier-free

    // ---- phase 3: screen all 512 codes, B-frags direct from global (L2-hot) ----
    float m1[8], m2[8]; int t1[8];
#pragma unroll
    for (int i = 0; i < 8; ++i) { m1[i] = 3.4e38f; m2[i] = 3.4e38f; t1[i] = 0; }

    {
        const unsigned short* wbl = wsb + ln * 8;   // per-lane frag base
#pragma unroll 2
        for (int t = 0; t < 32; ++t) {
            const unsigned short* nb = wbl + t * 2048;
            bf16x8 Bh0 = *(const bf16x8*)(nb + 0);
            bf16x8 Bl0 = *(const bf16x8*)(nb + 512);
            bf16x8 Bh1 = *(const bf16x8*)(nb + 1024);
            bf16x8 Bl1 = *(const bf16x8*)(nb + 1536);
            float cbv = s_cbsqr[t * 16 + m];
#pragma unroll
            for (int rt = 0; rt < 2; ++rt) {
                f32x4 acc = {0.f, 0.f, 0.f, 0.f};
                acc = __builtin_amdgcn_mfma_f32_16x16x32_bf16(Al[rt*2+0], Bh0, acc, 0,0,0);
                acc = __builtin_amdgcn_mfma_f32_16x16x32_bf16(Ah[rt*2+0], Bl0, acc, 0,0,0);
                acc = __builtin_amdgcn_mfma_f32_16x16x32_bf16(Ah[rt*2+0], Bh0, acc, 0,0,0);
                acc = __builtin_amdgcn_mfma_f32_16x16x32_bf16(Al[rt*2+1], Bh1, acc, 0,0,0);
                acc = __builtin_amdgcn_mfma_f32_16x16x32_bf16(Ah[rt*2+1], Bl1, acc, 0,0,0);
                acc = __builtin_amdgcn_mfma_f32_16x16x32_bf16(Ah[rt*2+1], Bh1, acc, 0,0,0);
#pragma unroll
                for (int r = 0; r < 4; ++r) {
                    float sc = fmaf(-2.f, acc[r], cbv);
                    int cell = rt * 4 + r;
                    bool lt = sc < m1[cell];
                    m2[cell] = fminf(m2[cell], lt ? m1[cell] : sc);
                    if (lt) { m1[cell] = sc; t1[cell] = t; }
                }
            }
        }
    }

    // ---- phase 4: per-position reduce over 16 lanes; flag ambiguity ----
#pragma unroll
    for (int cell = 0; cell < 8; ++cell) {
        int rt = cell >> 2, r = cell & 3;
        float v1 = m1[cell], v2 = m2[cell];
        int i1 = t1[cell] * 16 + m;
#pragma unroll
        for (int s = 1; s < 16; s <<= 1) {
            float o1 = __shfl_xor(v1, s);
            float o2 = __shfl_xor(v2, s);
            int   oi = __shfl_xor(i1, s);
            bool take = (o1 < v1) || (o1 == v1 && oi < i1);
            float lose = take ? v1 : o1;
            if (take) { v1 = o1; i1 = oi; }
            v2 = fminf(fminf(v2, o2), lose);
        }
        if (m == 0) {
            int pos = wv * 32 + rt * 16 + q * 4 + r;
            float xs = s_xsqr[pos];
            float sx = 8.0f * sqrtf(xs) * 1.01f;       // >= sum |x_d|
            float amax = 0.00196f * sx + 0.01f;        // >= sum|x c| + margin
            float eps = 1.5f * (3.0f * 1.52587890625e-5f * 0.00196f * sx
                                + 500.f * 5.96e-8f * amax);
            float delta = 2.4e-7f * (xs + 1.0f) + 64.f * 1.2e-7f * amax;
            float W = 2.f * eps + 2.f * delta + 1e-9f;
            int flag = (v2 - v1 <= W) ? (1 << 30) : 0;
            s_idx[pos] = i1 | flag;
        }
    }
    __syncthreads();
    if (tid < POSB) {
        if (s_idx[tid] & (1 << 30)) {
            int slot = atomicAdd(&s_cnt, 1);
            s_flist[slot] = tid;
        }
    }
    __syncthreads();

    // ---- phase 5: np-exact refine of flagged positions (x read from LDS) ----
    const int cnt = s_cnt;
    for (int i = wv; i < cnt; i += 4) {
        int p = __builtin_amdgcn_readfirstlane(s_flist[i]);
        float xv = s_regA[ln * S_X + p];             // lane ln holds x[d=ln]
        float xs = s_xsqr[p];
        float dot[8];
#pragma unroll
        for (int j = 0; j < 8; ++j) dot[j] = 0.f;
        const float* crow = cb + (ln * 8) * DDIM;    // lane's 8 codes
        for (int dc = 0; dc < 16; ++dc) {
            float x0 = __shfl(xv, dc*4 + 0);
            float x1 = __shfl(xv, dc*4 + 1);
            float x2 = __shfl(xv, dc*4 + 2);
            float x3 = __shfl(xv, dc*4 + 3);
#pragma unroll
            for (int j = 0; j < 8; ++j) {
                float4 cv = *(const float4*)(crow + j * DDIM + dc * 4);
                dot[j] = fmaf(x0, cv.x, dot[j]);
                dot[j] = fmaf(x1, cv.y, dot[j]);
                dot[j] = fmaf(x2, cv.z, dot[j]);
                dot[j] = fmaf(x3, cv.w, dot[j]);
            }
        }
        float bv = 3.4e38f; int bi = 0;
#pragma unroll
        for (int j = 0; j < 8; ++j) {
            int k = ln * 8 + j;
            float tt = s_cbsqr[k] + xs;
            float e = fmaf(-2.f, dot[j], tt);
            if (e < bv) { bv = e; bi = k; }
        }
#pragma unroll
        for (int s = 1; s < 64; s <<= 1) {
            float ov = __shfl_xor(bv, s); int oi = __shfl_xor(bi, s);
            if (ov < bv || (ov == bv && oi < bi)) { bv = ov; bi = oi; }
        }
        if (ln == 0) s_idx[p] = bi;
    }
    __syncthreads();   // s_idx final

    // ---- handoff: idx ints -> block's own copy-1 d=0 row (coalesced 512 B) ----
    if (tid < POSB)
        ((int*)out)[gbase + tid] = s_idx[tid] & 0x3FFFFFFF;
}

// ---------------- kernel B: P6 (gather codes + writeback both outputs) -------
__global__ __launch_bounds__(256, 4) void vq_scatter(
    const float* __restrict__ cb, float* __restrict__ out)
{
    __shared__ float s_codes[DDIM * S_X];   // 33792 B
    __shared__ int   s_pidx[POSB];

    const int tid = threadIdx.x;
    const int n0 = blockIdx.x * POSB;
    const long gbase = (long)(n0 >> 12) * (DDIM * HWSZ) + (n0 & 4095);

    // read back this block's own idx row (written by vq_screen)
    if (tid < POSB) s_pidx[tid] = ((const int*)out)[gbase + tid];
    __syncthreads();   // all idx consumed before any output writes

    // ---- gather selected code rows into LDS, d-major [d][pos] ----
    {
        int p = tid & 127, hf = tid >> 7;
        int idx = s_pidx[p];
        const float4* crow4 = (const float4*)(cb + idx * DDIM + hf * 32);
#pragma unroll
        for (int j4 = 0; j4 < 8; ++j4) {
            float4 cv = crow4[j4];
            int d = hf * 32 + j4 * 4;
            s_codes[(d + 0) * S_X + p] = cv.x;   // fixed d per instr, p per lane:
            s_codes[(d + 1) * S_X + p] = cv.y;   // consecutive banks, conflict-free
            s_codes[(d + 2) * S_X + p] = cv.z;
            s_codes[(d + 3) * S_X + p] = cv.w;
        }
    }
    __syncthreads();

    // ---- float4 writeback to both outputs (NCHW) ----
    {
        float4* o4 = (float4*)(out + gbase);
        const float4* c4 = (const float4*)s_codes;
#pragma unroll
        for (int i = 0; i < 8; ++i) {
            int v = i * 256 + tid;
            int d = v >> 5, p4 = v & 31;
            float4 val = c4[d * S_X4 + p4];
            size_t off = (size_t)d * (HWSZ / 4) + p4;
            o4[off] = val;
            o4[off + (OUT2_OFF / 4)] = val;
        }
    }
}

extern "C" void kernel_launch(void* const* d_in, const int* in_sizes, int n_in,
                              void* d_out, int out_size, void* d_ws, size_t ws_size,
                              hipStream_t stream) {
    const float* z  = (const float*)d_in[0];   // [32,64,64,64] fp32
    const float* cb = (const float*)d_in[1];   // [512,64] fp32
    float* out = (float*)d_out;                // 2 * 8388608 fp32
    unsigned short* wsb = (unsigned short*)d_ws;            // 128 KB frags
    float* wscb = (float*)((char*)d_ws + 131072);           // 2 KB cbsqr
    vq_prep<<<130, 256, 0, stream>>>(cb, wsb, wscb);
    vq_screen<<<NBLK, 256, 0, stream>>>(z, cb, wsb, wscb, out);
    vq_scatter<<<NBLK, 256, 0, stream>>>(cb, out);
}

// Round 9
// 178.281 us; speedup vs baseline: 1.1338x; 1.0240x over previous
//
#include <hip/hip_runtime.h>

// VQ-VAE codebook quantization — MFMA-screened, np-bit-exact.
// Screen: split-bf16 (xh+xl)(ch+cl) via mfma_f32_16x16x32_bf16, 3 terms.
// Sound window W flags possible np-argmin ambiguity; flagged positions
// re-scanned with the exact np fp32 pipeline.
//
// R9: occupancy via LDS, not registers. R8 attribution: P1-P5 = ~98us of
// the cost, scatter ~15us; fused beats split -> revert to R4 fused base.
// Fresh read of R4's constraints: VGPR=60 (<=64 -> 8-wave/SIMD class
// already); binding limit is LDS 38.9KB x4 = 155KB. R7 raised occupancy
// by squeezing registers (spilled); R9 shrinks LDS instead:
// POSB 128->64, grid 2048, LDS ~20.7KB -> 7 blocks/CU = 28 waves/CU
// (1.75x TLP). Each wave owns ONE 16x16 tile (R4's rt-slice): per-wave
// regs DROP (A-frags 16, min-track 12, 1 acc). Per-position MFMA chain
// order identical to R4 -> bit-exact.
// Canaries: VGPR_Count<=64, WRITE_SIZE==65536 KB exactly.

typedef short bf16x8 __attribute__((ext_vector_type(8)));
typedef float f32x4  __attribute__((ext_vector_type(4)));

#define KCODES 512
#define DDIM 64
#define HWSZ 4096
#define NPOS 131072
#define POSB 64              // positions per block (halved)
#define NBLK (NPOS / POSB)   // 2048 blocks
#define OUT2_OFF 8388608
#define S_X 68               // x_lds pos-stride in floats (mult of 4: aligned b128)
#define S_X4 (S_X / 4)       // float4 stride = 17

__device__ __forceinline__ unsigned short f2bf_rne(float f) {
    unsigned u = __builtin_bit_cast(unsigned, f);
    unsigned r = u + 0x7FFFu + ((u >> 16) & 1u);
    return (unsigned short)(r >> 16);
}
__device__ __forceinline__ float bf2f(unsigned short h) {
    unsigned u = ((unsigned)h) << 16;
    return __builtin_bit_cast(float, u);
}

// numpy pairwise_sum (n=64 branch) of rounded squares, fp32, no fma.
__device__ __forceinline__ float np_sumsq64(const float* __restrict__ a) {
#pragma clang fp contract(off)
    float r0 = a[0]*a[0], r1 = a[1]*a[1], r2 = a[2]*a[2], r3 = a[3]*a[3];
    float r4 = a[4]*a[4], r5 = a[5]*a[5], r6 = a[6]*a[6], r7 = a[7]*a[7];
#pragma unroll
    for (int i = 8; i < 64; i += 8) {
        r0 += a[i+0]*a[i+0]; r1 += a[i+1]*a[i+1];
        r2 += a[i+2]*a[i+2]; r3 += a[i+3]*a[i+3];
        r4 += a[i+4]*a[i+4]; r5 += a[i+5]*a[i+5];
        r6 += a[i+6]*a[i+6]; r7 += a[i+7]*a[i+7];
    }
    return ((r0+r1)+(r2+r3)) + ((r4+r5)+(r6+r7));
}

// Prep: B-fragments (split bf16) in exact 16x16x32 B-operand layout + np cbsqr.
// ws layout: [0,128KB) bf16 frags [tile32][chunk2][split2][lane64][j8];
//            [128KB,130KB) fp32 cbsqr[512].
__global__ __launch_bounds__(256) void vq_prep(
    const float* __restrict__ cb, unsigned short* __restrict__ wsb,
    float* __restrict__ wscb)
{
    if (blockIdx.x < 128) {
        int u = blockIdx.x * 256 + threadIdx.x;   // u = k*64 + d
        int k = u >> 6, d = u & 63;
        float c = cb[u];
        unsigned short ch = f2bf_rne(c);
        float clf = c - bf2f(ch);                  // exact
        unsigned short cl = f2bf_rne(clf);
        int tile = k >> 4, n = k & 15;
        int chunk = d >> 5, quad = (d >> 3) & 3, j = d & 7;
        int lane = quad * 16 + n;                  // B: lane holds B[k=q*8+j][n]
        size_t base = ((((size_t)tile*2 + chunk)*2 + 0)*64 + lane)*8 + j;
        wsb[base]       = (unsigned short)ch;
        wsb[base + 512] = (unsigned short)cl;      // split stride = 64*8
    } else {
        int k = (blockIdx.x - 128) * 256 + threadIdx.x;
        if (k < KCODES) wscb[k] = np_sumsq64(cb + k * DDIM);
    }
}

__global__ __launch_bounds__(256, 4) void vq_main(
    const float* __restrict__ z, const float* __restrict__ cb,
    const unsigned short* __restrict__ wsb, const float* __restrict__ wscb,
    float* __restrict__ out)
{
#pragma clang fp contract(off)
    __shared__ float4 s_xbuf4[DDIM * S_X4];   // 17408 B: x tile, reused for codes in P6
    __shared__ float s_cbsqr[KCODES];
    __shared__ float s_xsqr[POSB];
    __shared__ float s_part[2 * POSB];
    __shared__ int   s_idx[POSB];
    __shared__ int   s_flist[POSB];
    __shared__ int   s_cnt;
    float* s_regA = (float*)s_xbuf4;
    // total LDS ~20.7 KB -> 7 blocks/CU = 28 waves/CU (VGPR<=64 permitting)

    const int tid = threadIdx.x;
    const int wv = tid >> 6, ln = tid & 63;     // wave owns 16 positions wv*16..+15
    const int m = ln & 15, q = ln >> 4;
    const int n0 = blockIdx.x * POSB;
    const long gbase = (long)(n0 >> 12) * (DDIM * HWSZ) + (n0 & 4095);

    if (tid == 0) s_cnt = 0;
    s_cbsqr[tid] = wscb[tid];
    s_cbsqr[tid + 256] = wscb[tid + 256];

    // ---- phase 1: z -> x_lds, d-major [d][pos], float4 coalesced ----
    {
        const float4* z4 = (const float4*)(z + gbase);  // gbase mult of 64 -> 256B aligned
#pragma unroll
        for (int i = 0; i < 4; ++i) {
            int v = i * 256 + tid;          // 1024 float4 total (64 d x 16)
            int d = v >> 4, p4 = v & 15;
            s_xbuf4[d * S_X4 + p4] = z4[d * (HWSZ / 4) + p4];
        }
    }
    __syncthreads();

    // ---- phase 2a: np xsqr partials (128 threads -> (p, h)) ----
    if (tid < 128) {
        int p = tid & 63, h = tid >> 6;
        float r0 = 0.f, r1 = 0.f, r2 = 0.f, r3 = 0.f;
#pragma unroll
        for (int i = 0; i < 8; ++i) {
            float a0 = s_regA[(8*i + 4*h + 0) * S_X + p];
            float a1 = s_regA[(8*i + 4*h + 1) * S_X + p];
            float a2 = s_regA[(8*i + 4*h + 2) * S_X + p];
            float a3 = s_regA[(8*i + 4*h + 3) * S_X + p];
            r0 += a0*a0; r1 += a1*a1; r2 += a2*a2; r3 += a3*a3;
        }
        s_part[h * POSB + p] = (r0 + r1) + (r2 + r3);
    }

    // ---- phase 2b: A-fragments (per wave: 1 row-tile x 2 K-chunks, split) ----
    bf16x8 Ah[2], Al[2];
#pragma unroll
    for (int c = 0; c < 2; ++c) {
        int pos = wv * 16 + m;
        bf16x8 ah, al;
#pragma unroll
        for (int j = 0; j < 8; ++j) {
            float xv = s_regA[(c*32 + q*8 + j) * S_X + pos];
            unsigned short hh = f2bf_rne(xv);
            float lo = xv - bf2f(hh);          // exact
            ah[j] = (short)hh;
            al[j] = (short)f2bf_rne(lo);
        }
        Ah[c] = ah; Al[c] = al;
    }
    __syncthreads();
    if (tid < POSB) s_xsqr[tid] = s_part[tid] + s_part[POSB + tid]; // np (A+B)
    __syncthreads();   // s_xsqr visible to all (P4 readers); P3 is barrier-free

    // ---- phase 3: screen all 512 codes, B-frags direct from global (L2-hot) ----
    float m1[4], m2[4]; int t1[4];
#pragma unroll
    for (int i = 0; i < 4; ++i) { m1[i] = 3.4e38f; m2[i] = 3.4e38f; t1[i] = 0; }

    {
        const unsigned short* wbl = wsb + ln * 8;   // per-lane frag base
#pragma unroll 2
        for (int t = 0; t < 32; ++t) {
            const unsigned short* nb = wbl + t * 2048;
            bf16x8 Bh0 = *(const bf16x8*)(nb + 0);
            bf16x8 Bl0 = *(const bf16x8*)(nb + 512);
            bf16x8 Bh1 = *(const bf16x8*)(nb + 1024);
            bf16x8 Bl1 = *(const bf16x8*)(nb + 1536);
            float cbv = s_cbsqr[t * 16 + m];
            // identical accumulation order to R4's per-rt chain -> bit-exact
            f32x4 acc = {0.f, 0.f, 0.f, 0.f};
            acc = __builtin_amdgcn_mfma_f32_16x16x32_bf16(Al[0], Bh0, acc, 0,0,0);
            acc = __builtin_amdgcn_mfma_f32_16x16x32_bf16(Ah[0], Bl0, acc, 0,0,0);
            acc = __builtin_amdgcn_mfma_f32_16x16x32_bf16(Ah[0], Bh0, acc, 0,0,0);
            acc = __builtin_amdgcn_mfma_f32_16x16x32_bf16(Al[1], Bh1, acc, 0,0,0);
            acc = __builtin_amdgcn_mfma_f32_16x16x32_bf16(Ah[1], Bl1, acc, 0,0,0);
            acc = __builtin_amdgcn_mfma_f32_16x16x32_bf16(Ah[1], Bh1, acc, 0,0,0);
#pragma unroll
            for (int r = 0; r < 4; ++r) {
                float sc = fmaf(-2.f, acc[r], cbv);
                bool lt = sc < m1[r];
                m2[r] = fminf(m2[r], lt ? m1[r] : sc);
                if (lt) { m1[r] = sc; t1[r] = t; }
            }
        }
    }

    // ---- phase 4: per-position reduce over 16 lanes; flag ambiguity ----
#pragma unroll
    for (int r = 0; r < 4; ++r) {
        float v1 = m1[r], v2 = m2[r];
        int i1 = t1[r] * 16 + m;
#pragma unroll
        for (int s = 1; s < 16; s <<= 1) {
            float o1 = __shfl_xor(v1, s);
            float o2 = __shfl_xor(v2, s);
            int   oi = __shfl_xor(i1, s);
            bool take = (o1 < v1) || (o1 == v1 && oi < i1);
            float lose = take ? v1 : o1;
            if (take) { v1 = o1; i1 = oi; }
            v2 = fminf(fminf(v2, o2), lose);
        }
        if (m == 0) {
            int pos = wv * 16 + q * 4 + r;
            float xs = s_xsqr[pos];
            float sx = 8.0f * sqrtf(xs) * 1.01f;       // >= sum |x_d|
            float amax = 0.00196f * sx + 0.01f;        // >= sum|x c| + margin
            float eps = 1.5f * (3.0f * 1.52587890625e-5f * 0.00196f * sx
                                + 500.f * 5.96e-8f * amax);
            float delta = 2.4e-7f * (xs + 1.0f) + 64.f * 1.2e-7f * amax;
            float W = 2.f * eps + 2.f * delta + 1e-9f;
            int flag = (v2 - v1 <= W) ? (1 << 30) : 0;
            s_idx[pos] = i1 | flag;
        }
    }
    __syncthreads();
    if (tid < POSB) {
        if (s_idx[tid] & (1 << 30)) {
            int slot = atomicAdd(&s_cnt, 1);
            s_flist[slot] = tid;
        }
    }
    __syncthreads();

    // ---- phase 5: np-exact refine of flagged positions (x read from LDS) ----
    const int cnt = s_cnt;
    for (int i = wv; i < cnt; i += 4) {
        int p = __builtin_amdgcn_readfirstlane(s_flist[i]);
        float xv = s_regA[ln * S_X + p];             // lane ln holds x[d=ln]
        float xs = s_xsqr[p];
        float dot[8];
#pragma unroll
        for (int j = 0; j < 8; ++j) dot[j] = 0.f;
        const float* crow = cb + (ln * 8) * DDIM;    // lane's 8 codes
        for (int dc = 0; dc < 16; ++dc) {
            float x0 = __shfl(xv, dc*4 + 0);
            float x1 = __shfl(xv, dc*4 + 1);
            float x2 = __shfl(xv, dc*4 + 2);
            float x3 = __shfl(xv, dc*4 + 3);
#pragma unroll
            for (int j = 0; j < 8; ++j) {
                float4 cv = *(const float4*)(crow + j * DDIM + dc * 4);
                dot[j] = fmaf(x0, cv.x, dot[j]);
                dot[j] = fmaf(x1, cv.y, dot[j]);
                dot[j] = fmaf(x2, cv.z, dot[j]);
                dot[j] = fmaf(x3, cv.w, dot[j]);
            }
        }
        float bv = 3.4e38f; int bi = 0;
#pragma unroll
        for (int j = 0; j < 8; ++j) {
            int k = ln * 8 + j;
            float tt = s_cbsqr[k] + xs;
            float e = fmaf(-2.f, dot[j], tt);
            if (e < bv) { bv = e; bi = k; }
        }
#pragma unroll
        for (int s = 1; s < 64; s <<= 1) {
            float ov = __shfl_xor(bv, s); int oi = __shfl_xor(bi, s);
            if (ov < bv || (ov == bv && oi < bi)) { bv = ov; bi = oi; }
        }
        if (ln == 0) s_idx[p] = bi;
    }
    __syncthreads();   // P5 LDS reads done; s_idx final -> safe to overwrite s_regA

    // ---- phase 6a: stage selected code rows into LDS, d-major [d][pos] ----
    {
        int p = tid & 63, hf = tid >> 6;            // hf 0..3: 16 dims each
        int idx = s_idx[p] & 0x3FFFFFFF;
        const float4* crow4 = (const float4*)(cb + idx * DDIM + hf * 16);
#pragma unroll
        for (int j4 = 0; j4 < 4; ++j4) {
            float4 cv = crow4[j4];
            int d = hf * 16 + j4 * 4;
            s_regA[(d + 0) * S_X + p] = cv.x;   // fixed d per instr, p per lane:
            s_regA[(d + 1) * S_X + p] = cv.y;   // consecutive banks, conflict-free
            s_regA[(d + 2) * S_X + p] = cv.z;
            s_regA[(d + 3) * S_X + p] = cv.w;
        }
    }
    __syncthreads();

    // ---- phase 6b: float4 writeback to both outputs (NCHW) ----
    {
        float4* o4 = (float4*)(out + gbase);
#pragma unroll
        for (int i = 0; i < 4; ++i) {
            int v = i * 256 + tid;          // 1024 float4 total
            int d = v >> 4, p4 = v & 15;
            float4 val = s_xbuf4[d * S_X4 + p4];
            size_t off = (size_t)d * (HWSZ / 4) + p4;
            o4[off] = val;
            o4[off + (OUT2_OFF / 4)] = val;
        }
    }
}

extern "C" void kernel_launch(void* const* d_in, const int* in_sizes, int n_in,
                              void* d_out, int out_size, void* d_ws, size_t ws_size,
                              hipStream_t stream) {
    const float* z  = (const float*)d_in[0];   // [32,64,64,64] fp32
    const float* cb = (const float*)d_in[1];   // [512,64] fp32
    float* out = (float*)d_out;                // 2 * 8388608 fp32
    unsigned short* wsb = (unsigned short*)d_ws;            // 128 KB frags
    float* wscb = (float*)((char*)d_ws + 131072);           // 2 KB cbsqr
    vq_prep<<<130, 256, 0, stream>>>(cb, wsb, wscb);
    vq_main<<<NBLK, 256, 0, stream>>>(z, cb, wsb, wscb, out);
}

// Round 10
// 151.222 us; speedup vs baseline: 1.3367x; 1.1789x over previous
//
#include <hip/hip_runtime.h>

// VQ-VAE codebook quantization — MFMA-screened, np-bit-exact.
// Screen: split-bf16 (xh+xl)(ch+cl) via mfma_f32_16x16x32_bf16, 3 terms.
// Sound window W flags possible np-argmin ambiguity; flagged positions
// re-scanned with the exact np fp32 pipeline.
//
// R10 = R4 base + LDS-staged B-frags. Evidence chain: VALU-busy (~20us)
// and MFMA-busy (~10us) constant across R0/R4/R8/R9; duration tracks
// per-wave B-frag L2 streaming (R9: doubling it -> +33us; R6 L1-align
// null because 4 blocks x 32KB windows >> 32KB L1). Fix: stage the frag
// stream in LDS once per block (4x less L2 traffic), read via
// ds_read_b128 (lane-contiguous, conflict-free).
//  - P5 reads x from global z (R0's proven line) -> x-LDS dead after P2b,
//    reused as 2x16KB ping-pong staging windows.
//  - Staging via __builtin_amdgcn_global_load_lds width=16 (async, no
//    VGPR round-trip); wave wv stages tile ch*4+wv (no redundancy);
//    prefetch 1 chunk ahead; vmcnt(0)+barrier per chunk (9 barriers,
//    cheap per R5).
// All numerics byte-identical to R4 -> bit-exact.
// Canaries: VGPR<=64, WRITE_SIZE==65536 KB exactly.

typedef short bf16x8 __attribute__((ext_vector_type(8)));
typedef float f32x4  __attribute__((ext_vector_type(4)));

#define KCODES 512
#define DDIM 64
#define HWSZ 4096
#define NPOS 131072
#define POSB 128             // positions per block
#define NBLK (NPOS / POSB)   // 1024 = 256 CU x 4 blocks/CU (one resident round)
#define OUT2_OFF 8388608
#define S_X 132              // x_lds pos-stride in floats (mult of 4: aligned b128)
#define S_X4 (S_X / 4)       // float4 stride = 33

#define GLD_LDS16(gsrc, ldst)                                                   \
    __builtin_amdgcn_global_load_lds(                                           \
        (const __attribute__((address_space(1))) void*)(gsrc),                  \
        (__attribute__((address_space(3))) void*)(ldst), 16, 0, 0)

__device__ __forceinline__ unsigned short f2bf_rne(float f) {
    unsigned u = __builtin_bit_cast(unsigned, f);
    unsigned r = u + 0x7FFFu + ((u >> 16) & 1u);
    return (unsigned short)(r >> 16);
}
__device__ __forceinline__ float bf2f(unsigned short h) {
    unsigned u = ((unsigned)h) << 16;
    return __builtin_bit_cast(float, u);
}

// numpy pairwise_sum (n=64 branch) of rounded squares, fp32, no fma.
__device__ __forceinline__ float np_sumsq64(const float* __restrict__ a) {
#pragma clang fp contract(off)
    float r0 = a[0]*a[0], r1 = a[1]*a[1], r2 = a[2]*a[2], r3 = a[3]*a[3];
    float r4 = a[4]*a[4], r5 = a[5]*a[5], r6 = a[6]*a[6], r7 = a[7]*a[7];
#pragma unroll
    for (int i = 8; i < 64; i += 8) {
        r0 += a[i+0]*a[i+0]; r1 += a[i+1]*a[i+1];
        r2 += a[i+2]*a[i+2]; r3 += a[i+3]*a[i+3];
        r4 += a[i+4]*a[i+4]; r5 += a[i+5]*a[i+5];
        r6 += a[i+6]*a[i+6]; r7 += a[i+7]*a[i+7];
    }
    return ((r0+r1)+(r2+r3)) + ((r4+r5)+(r6+r7));
}

// Prep: B-fragments (split bf16) in exact 16x16x32 B-operand layout + np cbsqr.
// ws layout: [0,128KB) bf16 frags [tile32][chunk2][split2][lane64][j8];
//            [128KB,130KB) fp32 cbsqr[512].
__global__ __launch_bounds__(256) void vq_prep(
    const float* __restrict__ cb, unsigned short* __restrict__ wsb,
    float* __restrict__ wscb)
{
    if (blockIdx.x < 128) {
        int u = blockIdx.x * 256 + threadIdx.x;   // u = k*64 + d
        int k = u >> 6, d = u & 63;
        float c = cb[u];
        unsigned short ch = f2bf_rne(c);
        float clf = c - bf2f(ch);                  // exact
        unsigned short cl = f2bf_rne(clf);
        int tile = k >> 4, n = k & 15;
        int chunk = d >> 5, quad = (d >> 3) & 3, j = d & 7;
        int lane = quad * 16 + n;                  // B: lane holds B[k=q*8+j][n]
        size_t base = ((((size_t)tile*2 + chunk)*2 + 0)*64 + lane)*8 + j;
        wsb[base]       = (unsigned short)ch;
        wsb[base + 512] = (unsigned short)cl;      // split stride = 64*8
    } else {
        int k = (blockIdx.x - 128) * 256 + threadIdx.x;
        if (k < KCODES) wscb[k] = np_sumsq64(cb + k * DDIM);
    }
}

__global__ __launch_bounds__(256, 4) void vq_main(
    const float* __restrict__ z, const float* __restrict__ cb,
    const unsigned short* __restrict__ wsb, const float* __restrict__ wscb,
    float* __restrict__ out)
{
#pragma clang fp contract(off)
    __shared__ float4 s_xbuf4[DDIM * S_X4];   // 33792 B: x tile -> frag staging -> codes
    __shared__ float s_cbsqr[KCODES];
    __shared__ float s_xsqr[POSB];
    __shared__ float s_part[2 * POSB];
    __shared__ int   s_idx[POSB];
    __shared__ int   s_flist[POSB];
    __shared__ int   s_cnt;
    float* s_regA = (float*)s_xbuf4;
    // total LDS ~38.9 KB -> 4 blocks/CU (16 waves/CU)

    const int tid = threadIdx.x;
    const int wv = tid >> 6, ln = tid & 63;
    const int m = ln & 15, q = ln >> 4;
    const int n0 = blockIdx.x * POSB;
    const long gbase = (long)(n0 >> 12) * (DDIM * HWSZ) + (n0 & 4095);

    if (tid == 0) s_cnt = 0;
    s_cbsqr[tid] = wscb[tid];
    s_cbsqr[tid + 256] = wscb[tid + 256];

    // ---- phase 1: z -> x_lds, d-major [d][pos], float4 coalesced ----
    {
        const float4* z4 = (const float4*)(z + gbase);  // gbase mult of 128 -> aligned
#pragma unroll
        for (int i = 0; i < 8; ++i) {
            int v = i * 256 + tid;
            int d = v >> 5, p4 = v & 31;
            s_xbuf4[d * S_X4 + p4] = z4[d * (HWSZ / 4) + p4];
        }
    }
    __syncthreads();

    // ---- phase 2a: np xsqr partials (thread -> (p, h)) ----
    {
        int p = tid & 127, h = tid >> 7;
        float r0 = 0.f, r1 = 0.f, r2 = 0.f, r3 = 0.f;
#pragma unroll
        for (int i = 0; i < 8; ++i) {
            float a0 = s_regA[(8*i + 4*h + 0) * S_X + p];
            float a1 = s_regA[(8*i + 4*h + 1) * S_X + p];
            float a2 = s_regA[(8*i + 4*h + 2) * S_X + p];
            float a3 = s_regA[(8*i + 4*h + 3) * S_X + p];
            r0 += a0*a0; r1 += a1*a1; r2 += a2*a2; r3 += a3*a3;
        }
        s_part[h * POSB + p] = (r0 + r1) + (r2 + r3);
    }

    // ---- phase 2b: A-fragments (per wave: 2 row-tiles x 2 K-chunks, split) ----
    bf16x8 Ah[4], Al[4];
#pragma unroll
    for (int rt = 0; rt < 2; ++rt)
#pragma unroll
        for (int c = 0; c < 2; ++c) {
            int pos = wv * 32 + rt * 16 + m;
            bf16x8 ah, al;
#pragma unroll
            for (int j = 0; j < 8; ++j) {
                float xv = s_regA[(c*32 + q*8 + j) * S_X + pos];
                unsigned short hh = f2bf_rne(xv);
                float lo = xv - bf2f(hh);          // exact
                ah[j] = (short)hh;
                al[j] = (short)f2bf_rne(lo);
            }
            Ah[rt*2 + c] = ah; Al[rt*2 + c] = al;
        }
    __syncthreads();   // ALL x-tile reads complete -> buffer reusable for staging

    // ---- phase 3 prologue: stage chunk 0 (4 tiles, 16 KB) into buf0 ----
    // wave wv stages tile ch*4+wv: 4 x global_load_lds(16B) covering 4 KB.
    char* const stg0 = (char*)s_regA;
    char* const stg1 = (char*)s_regA + 16384;
    {
        const unsigned short* src = wsb + (0 * 4 + wv) * 2048 + ln * 8;
        char* dst = stg0 + wv * 4096;
#pragma unroll
        for (int i = 0; i < 4; ++i) GLD_LDS16(src + i * 512, dst + i * 1024);
    }
    if (tid < POSB) s_xsqr[tid] = s_part[tid] + s_part[POSB + tid]; // np (A+B)
    asm volatile("s_waitcnt vmcnt(0)" ::: "memory");
    __syncthreads();   // xsqr + chunk0 visible

    // ---- phase 3: screen all 512 codes; frags from LDS, dbuf prefetch ----
    float m1[8], m2[8]; int t1[8];
#pragma unroll
    for (int i = 0; i < 8; ++i) { m1[i] = 3.4e38f; m2[i] = 3.4e38f; t1[i] = 0; }

    {
        char* cur = stg0;
        char* nxt = stg1;
        for (int g = 0; g < 8; ++g) {
            if (g < 7) {   // prefetch next chunk into the other buffer (async)
                const unsigned short* src = wsb + ((g + 1) * 4 + wv) * 2048 + ln * 8;
                char* dst = nxt + wv * 4096;
#pragma unroll
                for (int i = 0; i < 4; ++i) GLD_LDS16(src + i * 512, dst + i * 1024);
            }
            const unsigned short* sb = (const unsigned short*)cur;
#pragma unroll
            for (int ti = 0; ti < 4; ++ti) {
                int t = g * 4 + ti;
                const unsigned short* s = sb + ti * 2048 + ln * 8;
                bf16x8 Bh0 = *(const bf16x8*)(s);
                bf16x8 Bl0 = *(const bf16x8*)(s + 512);
                bf16x8 Bh1 = *(const bf16x8*)(s + 1024);
                bf16x8 Bl1 = *(const bf16x8*)(s + 1536);
                float cbv = s_cbsqr[t * 16 + m];
#pragma unroll
                for (int rt = 0; rt < 2; ++rt) {
                    f32x4 acc = {0.f, 0.f, 0.f, 0.f};
                    acc = __builtin_amdgcn_mfma_f32_16x16x32_bf16(Al[rt*2+0], Bh0, acc, 0,0,0);
                    acc = __builtin_amdgcn_mfma_f32_16x16x32_bf16(Ah[rt*2+0], Bl0, acc, 0,0,0);
                    acc = __builtin_amdgcn_mfma_f32_16x16x32_bf16(Ah[rt*2+0], Bh0, acc, 0,0,0);
                    acc = __builtin_amdgcn_mfma_f32_16x16x32_bf16(Al[rt*2+1], Bh1, acc, 0,0,0);
                    acc = __builtin_amdgcn_mfma_f32_16x16x32_bf16(Ah[rt*2+1], Bl1, acc, 0,0,0);
                    acc = __builtin_amdgcn_mfma_f32_16x16x32_bf16(Ah[rt*2+1], Bh1, acc, 0,0,0);
#pragma unroll
                    for (int r = 0; r < 4; ++r) {
                        float sc = fmaf(-2.f, acc[r], cbv);
                        int cell = rt * 4 + r;
                        bool lt = sc < m1[cell];
                        m2[cell] = fminf(m2[cell], lt ? m1[cell] : sc);
                        if (lt) { m1[cell] = sc; t1[cell] = t; }
                    }
                }
            }
            asm volatile("s_waitcnt vmcnt(0)" ::: "memory");  // my prefetch landed
            __syncthreads();   // all waves done reading cur; next chunk visible
            char* tmp = cur; cur = nxt; nxt = tmp;
        }
    }

    // ---- phase 4: per-position reduce over 16 lanes; flag ambiguity ----
#pragma unroll
    for (int cell = 0; cell < 8; ++cell) {
        int rt = cell >> 2, r = cell & 3;
        float v1 = m1[cell], v2 = m2[cell];
        int i1 = t1[cell] * 16 + m;
#pragma unroll
        for (int s = 1; s < 16; s <<= 1) {
            float o1 = __shfl_xor(v1, s);
            float o2 = __shfl_xor(v2, s);
            int   oi = __shfl_xor(i1, s);
            bool take = (o1 < v1) || (o1 == v1 && oi < i1);
            float lose = take ? v1 : o1;
            if (take) { v1 = o1; i1 = oi; }
            v2 = fminf(fminf(v2, o2), lose);
        }
        if (m == 0) {
            int pos = wv * 32 + rt * 16 + q * 4 + r;
            float xs = s_xsqr[pos];
            float sx = 8.0f * sqrtf(xs) * 1.01f;       // >= sum |x_d|
            float amax = 0.00196f * sx + 0.01f;        // >= sum|x c| + margin
            float eps = 1.5f * (3.0f * 1.52587890625e-5f * 0.00196f * sx
                                + 500.f * 5.96e-8f * amax);
            float delta = 2.4e-7f * (xs + 1.0f) + 64.f * 1.2e-7f * amax;
            float W = 2.f * eps + 2.f * delta + 1e-9f;
            int flag = (v2 - v1 <= W) ? (1 << 30) : 0;
            s_idx[pos] = i1 | flag;
        }
    }
    __syncthreads();
    if (tid < POSB) {
        if (s_idx[tid] & (1 << 30)) {
            int slot = atomicAdd(&s_cnt, 1);
            s_flist[slot] = tid;
        }
    }
    __syncthreads();

    // ---- phase 5: np-exact refine of flagged positions (x from global z) ----
    const int cnt = s_cnt;
    for (int i = wv; i < cnt; i += 4) {
        int p = __builtin_amdgcn_readfirstlane(s_flist[i]);
        float xv = z[gbase + (long)ln * HWSZ + p];   // lane ln holds x[d=ln] (R0 line)
        float xs = s_xsqr[p];
        float dot[8];
#pragma unroll
        for (int j = 0; j < 8; ++j) dot[j] = 0.f;
        const float* crow = cb + (ln * 8) * DDIM;    // lane's 8 codes
        for (int dc = 0; dc < 16; ++dc) {
            float x0 = __shfl(xv, dc*4 + 0);
            float x1 = __shfl(xv, dc*4 + 1);
            float x2 = __shfl(xv, dc*4 + 2);
            float x3 = __shfl(xv, dc*4 + 3);
#pragma unroll
            for (int j = 0; j < 8; ++j) {
                float4 cv = *(const float4*)(crow + j * DDIM + dc * 4);
                dot[j] = fmaf(x0, cv.x, dot[j]);
                dot[j] = fmaf(x1, cv.y, dot[j]);
                dot[j] = fmaf(x2, cv.z, dot[j]);
                dot[j] = fmaf(x3, cv.w, dot[j]);
            }
        }
        float bv = 3.4e38f; int bi = 0;
#pragma unroll
        for (int j = 0; j < 8; ++j) {
            int k = ln * 8 + j;
            float tt = s_cbsqr[k] + xs;
            float e = fmaf(-2.f, dot[j], tt);
            if (e < bv) { bv = e; bi = k; }
        }
#pragma unroll
        for (int s = 1; s < 64; s <<= 1) {
            float ov = __shfl_xor(bv, s); int oi = __shfl_xor(bi, s);
            if (ov < bv || (ov == bv && oi < bi)) { bv = ov; bi = oi; }
        }
        if (ln == 0) s_idx[p] = bi;
    }
    __syncthreads();   // s_idx final -> safe to overwrite s_regA

    // ---- phase 6a: stage selected code rows into LDS, d-major [d][pos] ----
    {
        int p = tid & 127, hf = tid >> 7;
        int idx = s_idx[p] & 0x3FFFFFFF;
        const float4* crow4 = (const float4*)(cb + idx * DDIM + hf * 32);
#pragma unroll
        for (int j4 = 0; j4 < 8; ++j4) {
            float4 cv = crow4[j4];
            int d = hf * 32 + j4 * 4;
            s_regA[(d + 0) * S_X + p] = cv.x;   // fixed d per instr, p per lane:
            s_regA[(d + 1) * S_X + p] = cv.y;   // consecutive banks, conflict-free
            s_regA[(d + 2) * S_X + p] = cv.z;
            s_regA[(d + 3) * S_X + p] = cv.w;
        }
    }
    __syncthreads();

    // ---- phase 6b: float4 writeback to both outputs (NCHW) ----
    {
        float4* o4 = (float4*)(out + gbase);
#pragma unroll
        for (int i = 0; i < 8; ++i) {
            int v = i * 256 + tid;
            int d = v >> 5, p4 = v & 31;
            float4 val = s_xbuf4[d * S_X4 + p4];
            size_t off = (size_t)d * (HWSZ / 4) + p4;
            o4[off] = val;
            o4[off + (OUT2_OFF / 4)] = val;
        }
    }
}

extern "C" void kernel_launch(void* const* d_in, const int* in_sizes, int n_in,
                              void* d_out, int out_size, void* d_ws, size_t ws_size,
                              hipStream_t stream) {
    const float* z  = (const float*)d_in[0];   // [32,64,64,64] fp32
    const float* cb = (const float*)d_in[1];   // [512,64] fp32
    float* out = (float*)d_out;                // 2 * 8388608 fp32
    unsigned short* wsb = (unsigned short*)d_ws;            // 128 KB frags
    float* wscb = (float*)((char*)d_ws + 131072);           // 2 KB cbsqr
    vq_prep<<<130, 256, 0, stream>>>(cb, wsb, wscb);
    vq_main<<<NBLK, 256, 0, stream>>>(z, cb, wsb, wscb, out);
}

// Round 11
// 150.111 us; speedup vs baseline: 1.3466x; 1.0074x over previous
//
#include <hip/hip_runtime.h>

// VQ-VAE codebook quantization — MFMA-screened, np-bit-exact.
// Screen: split-bf16 (xh+xl)(ch+cl) via mfma_f32_16x16x32_bf16, 3 terms.
// Sound window W flags possible np-argmin ambiguity; flagged positions
// re-scanned with the exact np fp32 pipeline.
//
// R11 = clean retest of R10's L2-traffic theory. R10 evidence: LDS-staged
// B-frags held time at 83us DESPITE +17MB spill (R1's similar spill cost
// +23us) -> staging likely helps, spill masked it. Practical arch-VGPR
// ceiling at 4 blocks/CU is ~64 (R4=60 clean; R10=64 spilled; unified
// file shares with MFMA block). Minimal-state version:
//  - single 16KB staging buffer, SYNCHRONOUS per 4-tile chunk:
//    barrier -> wave wv stages tile g*4+wv (4x global_load_lds w=16)
//    -> vmcnt(0)+barrier -> compute. No dbuf/prefetch state. Exposed
//    latency ~8x300cyc ~ 1us; barriers cheap (R5/R6).
//  - B-frags read in HALVES (Bh0/Bl0 then Bh1/Bl1 reusing regs): -8 live
//    VGPRs; per-acc MFMA chain order identical to R4 -> bit-exact.
//  - P5 reads x from global z (R10 line) -> x-LDS free for staging.
// Validity gate: VGPR<=64 AND WRITE_SIZE==65536 KB exactly.
// If clean+null -> traffic theory dead -> R12 = 3-kernel attribution.

typedef short bf16x8 __attribute__((ext_vector_type(8)));
typedef float f32x4  __attribute__((ext_vector_type(4)));

#define KCODES 512
#define DDIM 64
#define HWSZ 4096
#define NPOS 131072
#define POSB 128             // positions per block
#define NBLK (NPOS / POSB)   // 1024 = 256 CU x 4 blocks/CU (one resident round)
#define OUT2_OFF 8388608
#define S_X 132              // x_lds pos-stride in floats (mult of 4: aligned b128)
#define S_X4 (S_X / 4)       // float4 stride = 33

#define GLD_LDS16(gsrc, ldst)                                                   \
    __builtin_amdgcn_global_load_lds(                                           \
        (const __attribute__((address_space(1))) void*)(gsrc),                  \
        (__attribute__((address_space(3))) void*)(ldst), 16, 0, 0)

__device__ __forceinline__ unsigned short f2bf_rne(float f) {
    unsigned u = __builtin_bit_cast(unsigned, f);
    unsigned r = u + 0x7FFFu + ((u >> 16) & 1u);
    return (unsigned short)(r >> 16);
}
__device__ __forceinline__ float bf2f(unsigned short h) {
    unsigned u = ((unsigned)h) << 16;
    return __builtin_bit_cast(float, u);
}

// numpy pairwise_sum (n=64 branch) of rounded squares, fp32, no fma.
__device__ __forceinline__ float np_sumsq64(const float* __restrict__ a) {
#pragma clang fp contract(off)
    float r0 = a[0]*a[0], r1 = a[1]*a[1], r2 = a[2]*a[2], r3 = a[3]*a[3];
    float r4 = a[4]*a[4], r5 = a[5]*a[5], r6 = a[6]*a[6], r7 = a[7]*a[7];
#pragma unroll
    for (int i = 8; i < 64; i += 8) {
        r0 += a[i+0]*a[i+0]; r1 += a[i+1]*a[i+1];
        r2 += a[i+2]*a[i+2]; r3 += a[i+3]*a[i+3];
        r4 += a[i+4]*a[i+4]; r5 += a[i+5]*a[i+5];
        r6 += a[i+6]*a[i+6]; r7 += a[i+7]*a[i+7];
    }
    return ((r0+r1)+(r2+r3)) + ((r4+r5)+(r6+r7));
}

// Prep: B-fragments (split bf16) in exact 16x16x32 B-operand layout + np cbsqr.
// ws layout: [0,128KB) bf16 frags [tile32][chunk2][split2][lane64][j8];
//            [128KB,130KB) fp32 cbsqr[512].
__global__ __launch_bounds__(256) void vq_prep(
    const float* __restrict__ cb, unsigned short* __restrict__ wsb,
    float* __restrict__ wscb)
{
    if (blockIdx.x < 128) {
        int u = blockIdx.x * 256 + threadIdx.x;   // u = k*64 + d
        int k = u >> 6, d = u & 63;
        float c = cb[u];
        unsigned short ch = f2bf_rne(c);
        float clf = c - bf2f(ch);                  // exact
        unsigned short cl = f2bf_rne(clf);
        int tile = k >> 4, n = k & 15;
        int chunk = d >> 5, quad = (d >> 3) & 3, j = d & 7;
        int lane = quad * 16 + n;                  // B: lane holds B[k=q*8+j][n]
        size_t base = ((((size_t)tile*2 + chunk)*2 + 0)*64 + lane)*8 + j;
        wsb[base]       = (unsigned short)ch;
        wsb[base + 512] = (unsigned short)cl;      // split stride = 64*8
    } else {
        int k = (blockIdx.x - 128) * 256 + threadIdx.x;
        if (k < KCODES) wscb[k] = np_sumsq64(cb + k * DDIM);
    }
}

__global__ __launch_bounds__(256, 4) void vq_main(
    const float* __restrict__ z, const float* __restrict__ cb,
    const unsigned short* __restrict__ wsb, const float* __restrict__ wscb,
    float* __restrict__ out)
{
#pragma clang fp contract(off)
    __shared__ float4 s_xbuf4[DDIM * S_X4];   // 33792 B: x tile -> frag staging -> codes
    __shared__ float s_cbsqr[KCODES];
    __shared__ float s_xsqr[POSB];
    __shared__ float s_part[2 * POSB];
    __shared__ int   s_idx[POSB];
    __shared__ int   s_flist[POSB];
    __shared__ int   s_cnt;
    float* s_regA = (float*)s_xbuf4;
    // total LDS ~38.9 KB -> 4 blocks/CU (16 waves/CU)

    const int tid = threadIdx.x;
    const int wv = tid >> 6, ln = tid & 63;
    const int m = ln & 15, q = ln >> 4;
    const int n0 = blockIdx.x * POSB;
    const long gbase = (long)(n0 >> 12) * (DDIM * HWSZ) + (n0 & 4095);

    if (tid == 0) s_cnt = 0;
    s_cbsqr[tid] = wscb[tid];
    s_cbsqr[tid + 256] = wscb[tid + 256];

    // ---- phase 1: z -> x_lds, d-major [d][pos], float4 coalesced ----
    {
        const float4* z4 = (const float4*)(z + gbase);  // gbase mult of 128 -> aligned
#pragma unroll
        for (int i = 0; i < 8; ++i) {
            int v = i * 256 + tid;
            int d = v >> 5, p4 = v & 31;
            s_xbuf4[d * S_X4 + p4] = z4[d * (HWSZ / 4) + p4];
        }
    }
    __syncthreads();

    // ---- phase 2a: np xsqr partials (thread -> (p, h)) ----
    {
        int p = tid & 127, h = tid >> 7;
        float r0 = 0.f, r1 = 0.f, r2 = 0.f, r3 = 0.f;
#pragma unroll
        for (int i = 0; i < 8; ++i) {
            float a0 = s_regA[(8*i + 4*h + 0) * S_X + p];
            float a1 = s_regA[(8*i + 4*h + 1) * S_X + p];
            float a2 = s_regA[(8*i + 4*h + 2) * S_X + p];
            float a3 = s_regA[(8*i + 4*h + 3) * S_X + p];
            r0 += a0*a0; r1 += a1*a1; r2 += a2*a2; r3 += a3*a3;
        }
        s_part[h * POSB + p] = (r0 + r1) + (r2 + r3);
    }

    // ---- phase 2b: A-fragments (per wave: 2 row-tiles x 2 K-chunks, split) ----
    bf16x8 Ah[4], Al[4];
#pragma unroll
    for (int rt = 0; rt < 2; ++rt)
#pragma unroll
        for (int c = 0; c < 2; ++c) {
            int pos = wv * 32 + rt * 16 + m;
            bf16x8 ah, al;
#pragma unroll
            for (int j = 0; j < 8; ++j) {
                float xv = s_regA[(c*32 + q*8 + j) * S_X + pos];
                unsigned short hh = f2bf_rne(xv);
                float lo = xv - bf2f(hh);          // exact
                ah[j] = (short)hh;
                al[j] = (short)f2bf_rne(lo);
            }
            Ah[rt*2 + c] = ah; Al[rt*2 + c] = al;
        }
    __syncthreads();   // ALL x-tile reads complete -> buffer reusable for staging
    if (tid < POSB) s_xsqr[tid] = s_part[tid] + s_part[POSB + tid]; // np (A+B)
    // (s_xsqr becomes visible to all at the first in-loop barrier below)

    // ---- phase 3: screen all 512 codes; B-frags LDS-staged per 4-tile chunk
    //      (single 16KB buffer, synchronous; wave wv stages tile g*4+wv) ----
    float m1[8], m2[8]; int t1[8];
#pragma unroll
    for (int i = 0; i < 8; ++i) { m1[i] = 3.4e38f; m2[i] = 3.4e38f; t1[i] = 0; }

    {
        char* const stg = (char*)s_regA;             // 16 KB staging window
        for (int g = 0; g < 8; ++g) {
            // stage: 4 x 16B per lane covers this wave's 4 KB tile
            {
                const unsigned short* src = wsb + (g * 4 + wv) * 2048 + ln * 8;
                char* dst = stg + wv * 4096;
#pragma unroll
                for (int i = 0; i < 4; ++i) GLD_LDS16(src + i * 512, dst + i * 1024);
            }
            asm volatile("s_waitcnt vmcnt(0)" ::: "memory");
            __syncthreads();   // chunk staged (g=0: also publishes s_xsqr)
#pragma unroll
            for (int ti = 0; ti < 4; ++ti) {
                int t = g * 4 + ti;
                const unsigned short* sB = (const unsigned short*)(stg + ti * 4096) + ln * 8;
                float cbv = s_cbsqr[t * 16 + m];
                f32x4 acc0 = {0.f, 0.f, 0.f, 0.f};
                f32x4 acc1 = {0.f, 0.f, 0.f, 0.f};
                // K-chunk 0 (same per-acc chain order as R4 -> bit-exact)
                bf16x8 Bh = *(const bf16x8*)(sB);
                bf16x8 Bl = *(const bf16x8*)(sB + 512);
                acc0 = __builtin_amdgcn_mfma_f32_16x16x32_bf16(Al[0], Bh, acc0, 0,0,0);
                acc0 = __builtin_amdgcn_mfma_f32_16x16x32_bf16(Ah[0], Bl, acc0, 0,0,0);
                acc0 = __builtin_amdgcn_mfma_f32_16x16x32_bf16(Ah[0], Bh, acc0, 0,0,0);
                acc1 = __builtin_amdgcn_mfma_f32_16x16x32_bf16(Al[2], Bh, acc1, 0,0,0);
                acc1 = __builtin_amdgcn_mfma_f32_16x16x32_bf16(Ah[2], Bl, acc1, 0,0,0);
                acc1 = __builtin_amdgcn_mfma_f32_16x16x32_bf16(Ah[2], Bh, acc1, 0,0,0);
                // K-chunk 1 (reuse Bh/Bl regs)
                Bh = *(const bf16x8*)(sB + 1024);
                Bl = *(const bf16x8*)(sB + 1536);
                acc0 = __builtin_amdgcn_mfma_f32_16x16x32_bf16(Al[1], Bh, acc0, 0,0,0);
                acc0 = __builtin_amdgcn_mfma_f32_16x16x32_bf16(Ah[1], Bl, acc0, 0,0,0);
                acc0 = __builtin_amdgcn_mfma_f32_16x16x32_bf16(Ah[1], Bh, acc0, 0,0,0);
                acc1 = __builtin_amdgcn_mfma_f32_16x16x32_bf16(Al[3], Bh, acc1, 0,0,0);
                acc1 = __builtin_amdgcn_mfma_f32_16x16x32_bf16(Ah[3], Bl, acc1, 0,0,0);
                acc1 = __builtin_amdgcn_mfma_f32_16x16x32_bf16(Ah[3], Bh, acc1, 0,0,0);
#pragma unroll
                for (int r = 0; r < 4; ++r) {
                    float sc = fmaf(-2.f, acc0[r], cbv);
                    bool lt = sc < m1[r];
                    m2[r] = fminf(m2[r], lt ? m1[r] : sc);
                    if (lt) { m1[r] = sc; t1[r] = t; }
                }
#pragma unroll
                for (int r = 0; r < 4; ++r) {
                    float sc = fmaf(-2.f, acc1[r], cbv);
                    int cell = 4 + r;
                    bool lt = sc < m1[cell];
                    m2[cell] = fminf(m2[cell], lt ? m1[cell] : sc);
                    if (lt) { m1[cell] = sc; t1[cell] = t; }
                }
            }
            __syncthreads();   // all waves done reading chunk before overwrite
        }
    }

    // ---- phase 4: per-position reduce over 16 lanes; flag ambiguity ----
#pragma unroll
    for (int cell = 0; cell < 8; ++cell) {
        int rt = cell >> 2, r = cell & 3;
        float v1 = m1[cell], v2 = m2[cell];
        int i1 = t1[cell] * 16 + m;
#pragma unroll
        for (int s = 1; s < 16; s <<= 1) {
            float o1 = __shfl_xor(v1, s);
            float o2 = __shfl_xor(v2, s);
            int   oi = __shfl_xor(i1, s);
            bool take = (o1 < v1) || (o1 == v1 && oi < i1);
            float lose = take ? v1 : o1;
            if (take) { v1 = o1; i1 = oi; }
            v2 = fminf(fminf(v2, o2), lose);
        }
        if (m == 0) {
            int pos = wv * 32 + rt * 16 + q * 4 + r;
            float xs = s_xsqr[pos];
            float sx = 8.0f * sqrtf(xs) * 1.01f;       // >= sum |x_d|
            float amax = 0.00196f * sx + 0.01f;        // >= sum|x c| + margin
            float eps = 1.5f * (3.0f * 1.52587890625e-5f * 0.00196f * sx
                                + 500.f * 5.96e-8f * amax);
            float delta = 2.4e-7f * (xs + 1.0f) + 64.f * 1.2e-7f * amax;
            float W = 2.f * eps + 2.f * delta + 1e-9f;
            int flag = (v2 - v1 <= W) ? (1 << 30) : 0;
            s_idx[pos] = i1 | flag;
        }
    }
    __syncthreads();
    if (tid < POSB) {
        if (s_idx[tid] & (1 << 30)) {
            int slot = atomicAdd(&s_cnt, 1);
            s_flist[slot] = tid;
        }
    }
    __syncthreads();

    // ---- phase 5: np-exact refine of flagged positions (x from global z) ----
    const int cnt = s_cnt;
    for (int i = wv; i < cnt; i += 4) {
        int p = __builtin_amdgcn_readfirstlane(s_flist[i]);
        float xv = z[gbase + (long)ln * HWSZ + p];   // lane ln holds x[d=ln]
        float xs = s_xsqr[p];
        float dot[8];
#pragma unroll
        for (int j = 0; j < 8; ++j) dot[j] = 0.f;
        const float* crow = cb + (ln * 8) * DDIM;    // lane's 8 codes
        for (int dc = 0; dc < 16; ++dc) {
            float x0 = __shfl(xv, dc*4 + 0);
            float x1 = __shfl(xv, dc*4 + 1);
            float x2 = __shfl(xv, dc*4 + 2);
            float x3 = __shfl(xv, dc*4 + 3);
#pragma unroll
            for (int j = 0; j < 8; ++j) {
                float4 cv = *(const float4*)(crow + j * DDIM + dc * 4);
                dot[j] = fmaf(x0, cv.x, dot[j]);
                dot[j] = fmaf(x1, cv.y, dot[j]);
                dot[j] = fmaf(x2, cv.z, dot[j]);
                dot[j] = fmaf(x3, cv.w, dot[j]);
            }
        }
        float bv = 3.4e38f; int bi = 0;
#pragma unroll
        for (int j = 0; j < 8; ++j) {
            int k = ln * 8 + j;
            float tt = s_cbsqr[k] + xs;
            float e = fmaf(-2.f, dot[j], tt);
            if (e < bv) { bv = e; bi = k; }
        }
#pragma unroll
        for (int s = 1; s < 64; s <<= 1) {
            float ov = __shfl_xor(bv, s); int oi = __shfl_xor(bi, s);
            if (ov < bv || (ov == bv && oi < bi)) { bv = ov; bi = oi; }
        }
        if (ln == 0) s_idx[p] = bi;
    }
    __syncthreads();   // s_idx final -> safe to overwrite s_regA

    // ---- phase 6a: stage selected code rows into LDS, d-major [d][pos] ----
    {
        int p = tid & 127, hf = tid >> 7;
        int idx = s_idx[p] & 0x3FFFFFFF;
        const float4* crow4 = (const float4*)(cb + idx * DDIM + hf * 32);
#pragma unroll
        for (int j4 = 0; j4 < 8; ++j4) {
            float4 cv = crow4[j4];
            int d = hf * 32 + j4 * 4;
            s_regA[(d + 0) * S_X + p] = cv.x;   // fixed d per instr, p per lane:
            s_regA[(d + 1) * S_X + p] = cv.y;   // consecutive banks, conflict-free
            s_regA[(d + 2) * S_X + p] = cv.z;
            s_regA[(d + 3) * S_X + p] = cv.w;
        }
    }
    __syncthreads();

    // ---- phase 6b: float4 writeback to both outputs (NCHW) ----
    {
        float4* o4 = (float4*)(out + gbase);
#pragma unroll
        for (int i = 0; i < 8; ++i) {
            int v = i * 256 + tid;
            int d = v >> 5, p4 = v & 31;
            float4 val = s_xbuf4[d * S_X4 + p4];
            size_t off = (size_t)d * (HWSZ / 4) + p4;
            o4[off] = val;
            o4[off + (OUT2_OFF / 4)] = val;
        }
    }
}

extern "C" void kernel_launch(void* const* d_in, const int* in_sizes, int n_in,
                              void* d_out, int out_size, void* d_ws, size_t ws_size,
                              hipStream_t stream) {
    const float* z  = (const float*)d_in[0];   // [32,64,64,64] fp32
    const float* cb = (const float*)d_in[1];   // [512,64] fp32
    float* out = (float*)d_out;                // 2 * 8388608 fp32
    unsigned short* wsb = (unsigned short*)d_ws;            // 128 KB frags
    float* wscb = (float*)((char*)d_ws + 131072);           // 2 KB cbsqr
    vq_prep<<<130, 256, 0, stream>>>(cb, wsb, wscb);
    vq_main<<<NBLK, 256, 0, stream>>>(z, cb, wsb, wscb, out);
}